// Round 18
// baseline (1755.492 us; speedup 1.0000x reference)
//
#include <hip/hip_runtime.h>
#include <hip/hip_bf16.h>

#define BB 64
#define TT_ 512
#define IN_ 256
#define HH 1024
#define G4 4096
#define OO 256

typedef _Float16 half8 __attribute__((ext_vector_type(8)));
typedef float f32x4 __attribute__((ext_vector_type(4)));
typedef unsigned int uint4v __attribute__((ext_vector_type(4)));

__device__ __forceinline__ float sigmoidf_(float v) {
    return 1.f / (1.f + __expf(-v));
}
__device__ __forceinline__ float tanhf_(float v) {
    float vc = fminf(fmaxf(v, -15.f), 15.f);
    float e = __expf(2.f * vc);
    return (e - 1.f) / (e + 1.f);
}

// ---------------- fused pack kernel ----------------
// One launch does all weight/x packs + Hbuf poison (disjoint outputs).
// Block ranges:
//   [0,2560)      pack_a2   (enc [Whh|Wih] -> Apk, gate-interleaved 4dx4g tiles)
//   [2560,6656)   pack_x    (x -> Xpk B-frag-major per t)
//   [6656,6672)   bias enc  (ebih+ebhh -> biasc)
//   [6672,6688)   bias dec  (dbih+dbhh -> biascd)
//   [6688,7200)   pack_adec (dec Wih -> Adecpk)
//   [7200,7328)   pack_fcw  (fcW -> fcWpk)
//   [7328,9376)   pack_ahh  (dec Whh -> Ahhpk)
//   [9376,9888)   poison Hbuf (0xFFFFFFFF)
__global__ __launch_bounds__(256)
void pack_all(const float* __restrict__ eWhh, const float* __restrict__ eWih,
              const float* __restrict__ x,
              const float* __restrict__ ebih, const float* __restrict__ ebhh,
              const float* __restrict__ dbih, const float* __restrict__ dbhh,
              const float* __restrict__ dWih, const float* __restrict__ fcW,
              const float* __restrict__ dWhh,
              _Float16* __restrict__ Apk, _Float16* __restrict__ Xpk,
              float* __restrict__ biasc, float* __restrict__ biascd,
              _Float16* __restrict__ Adecpk, _Float16* __restrict__ fcWpk,
              _Float16* __restrict__ Ahhpk, _Float16* __restrict__ Hbuf)
{
    const int blk = blockIdx.x;
    if (blk < 2560) {
        int id = blk * 256 + threadIdx.x;             // < 655360
        int dq  = id / 5120;
        int r1  = id - dq * 5120;
        int t2  = r1 / 2560;
        int r2  = r1 - t2 * 2560;
        int kc  = r2 >> 6, l = r2 & 63;
        int rD  = l & 15;
        int g   = rD & 3, ddl = rD >> 2;
        int d   = dq * 8 + t2 * 4 + ddl;
        int j   = g * HH + d;
        int k0  = kc * 32 + ((l >> 4) << 3);
        half8 v;
        if (kc < 32) {
            const float* s = eWhh + (size_t)j * HH + k0;
#pragma unroll
            for (int e = 0; e < 8; ++e) v[e] = (_Float16)s[e];
        } else {
            const float* s = eWih + (size_t)j * IN_ + (k0 - 1024);
#pragma unroll
            for (int e = 0; e < 8; ++e) v[e] = (_Float16)s[e];
        }
        ((half8*)Apk)[id] = v;
    } else if (blk < 6656) {
        int id = (blk - 2560) * 256 + threadIdx.x;    // < 1048576
        int l = id & 63, bt = (id >> 6) & 3, kc2 = (id >> 8) & 7, t = id >> 11;
        int b  = bt * 16 + (l & 15);
        int i0 = kc2 * 32 + ((l >> 4) << 3);
        const float* s = x + ((size_t)b * TT_ + t) * IN_ + i0;
        half8 v;
#pragma unroll
        for (int e = 0; e < 8; ++e) v[e] = (_Float16)s[e];
        ((half8*)Xpk)[id] = v;
    } else if (blk < 6672) {
        int j = (blk - 6656) * 256 + threadIdx.x;
        if (j < G4) biasc[j] = ebih[j] + ebhh[j];
    } else if (blk < 6688) {
        int j = (blk - 6672) * 256 + threadIdx.x;
        if (j < G4) biascd[j] = dbih[j] + dbhh[j];
    } else if (blk < 7200) {
        int id = (blk - 6688) * 256 + threadIdx.x;    // < 131072
        int dq = id >> 10;
        int r1 = id & 1023;
        int t2 = r1 >> 9;
        int r2 = r1 & 511;
        int kc2 = r2 >> 6, l = r2 & 63;
        int rD = l & 15, g = rD & 3, ddl = rD >> 2;
        int d  = dq * 8 + t2 * 4 + ddl;
        int j  = g * HH + d;
        int k0 = kc2 * 32 + ((l >> 4) << 3);
        const float* s = dWih + (size_t)j * IN_ + k0;
        half8 v;
#pragma unroll
        for (int e = 0; e < 8; ++e) v[e] = (_Float16)s[e];
        ((half8*)Adecpk)[id] = v;
    } else if (blk < 7328) {
        int id = (blk - 7200) * 256 + threadIdx.x;    // < 32768
        int ot = id >> 11;
        int r  = id & 2047;
        int kc = r >> 6, l = r & 63;
        int o  = ot * 16 + (l & 15);
        int k0 = kc * 32 + ((l >> 4) << 3);
        const float* s = fcW + (size_t)o * HH + k0;
        half8 v;
#pragma unroll
        for (int e = 0; e < 8; ++e) v[e] = (_Float16)s[e];
        ((half8*)fcWpk)[id] = v;
    } else if (blk < 9376) {
        int id = (blk - 7328) * 256 + threadIdx.x;    // < 524288
        int jt = id >> 11;
        int r  = id & 2047;
        int kc = r >> 6, l = r & 63;
        int rD = l & 15, g = rD & 3, ddl = rD >> 2;
        int d  = jt * 4 + ddl;
        int j  = g * HH + d;
        int k0 = kc * 32 + ((l >> 4) << 3);
        const float* s = dWhh + (size_t)j * HH + k0;
        half8 v;
#pragma unroll
        for (int e = 0; e < 8; ++e) v[e] = (_Float16)s[e];
        ((half8*)Ahhpk)[id] = v;
    } else {
        // poison Hbuf: 512 blocks x 256 thr x 4 uint4v = 524288 uint4v = 8 MB
        uint4v* H4 = (uint4v*)Hbuf;
        int base = (blk - 9376) * 1024 + threadIdx.x;
        uint4v p = {0xFFFFFFFFu, 0xFFFFFFFFu, 0xFFFFFFFFu, 0xFFFFFFFFu};
#pragma unroll
        for (int i = 0; i < 4; ++i) H4[base + i * 256] = p;
    }
}

// ---------------- persistent encoder v13: R17 + pp double-buffer (1 barrier/step) ----------------
// grid 256 = (dq16 = bid>>2, grp = bid&3), block 256 (4 waves, 1 WG/CU).
// Register-resident H (tmp[i] IS B-frag kc=i*4+w); wave w computes partials
// for all 4 tiles over its 8 resident kc; pp[2] alternating buffers make the
// end-of-loop barrier unnecessary (write at t+2 ordered after read at t via
// the t+1 barrier). Poll = R15/R17's proven partial-re-issue form.
// Publish EVERY step: slot (TT_-1)&63 holds final h (B-frag) for hdec_mfma.
__global__ __launch_bounds__(256, 1)
void enc_persist(const _Float16* __restrict__ Apk,
                 const _Float16* __restrict__ Xpk,
                 _Float16* __restrict__ Hbuf,
                 const float* __restrict__ biasc,
                 float* __restrict__ cT)
{
    __shared__ __align__(16) _Float16 Ald[4 * 32 * 64 * 8];   // 128 KB
    __shared__ __align__(16) f32x4 pp[2][16 * 64];            // 32 KB (160 total)
    const int tid  = threadIdx.x;
    const int lane = tid & 63, w = tid >> 6;
    const int dq16 = blockIdx.x >> 2, grp = blockIdx.x & 3;
    const int q = lane >> 4, bl = lane & 15;
    const int d = dq16 * 16 + w * 4 + q;         // this thread's dim (own tile)
    const int b = grp * 16 + bl;                 // this thread's batch

    // ---- one-time: each wave loads its tile's 32 Whh A-frags -> LDS ----
    {
        const half8* src = (const half8*)Apk + ((size_t)(dq16 * 4 + w) * 40) * 64 + lane;
        half8* dst = (half8*)Ald + (size_t)w * 2048 + lane;
#pragma unroll
        for (int kc = 0; kc < 32; ++kc) dst[kc * 64] = src[kc * 64];
    }
    // ---- one-time: own tile's Wih A-frags -> registers (8 frags) ----
    half8 xa[8];
    {
        const half8* src = (const half8*)Apk + ((size_t)(dq16 * 4 + w) * 40 + 32) * 64 + lane;
#pragma unroll
        for (int k = 0; k < 8; ++k) xa[k] = src[k * 64];
    }

    float bsum[4];
#pragma unroll
    for (int g = 0; g < 4; ++g) bsum[g] = biasc[g * HH + d];

    const half8* Ald8 = (const half8*)Ald + lane;   // + jl*2048 + kc*64

    // publish half-index within a slot (pair of dims d, d^1 packed as u32),
    // in fp16 units; slot stride = 65536 fp16
    const unsigned int pidx = ((unsigned)grp * 2048 + ((unsigned)d >> 5) * 64 +
                               (((unsigned)d >> 3) & 3) * 16 + bl) * 8 + (d & 7);

    float c_reg = 0.f;
    __syncthreads();   // A-LDS ready

    for (int t = 0; t < TT_; ++t) {
        const int sIn  = (t - 1) & 63;
        const int sOut = t & 63;
        const int sPoi = (t + 8) & 63;
        const int pb   = t & 1;

        // ---- issue xf loads FIRST (plain), then H (sc0sc1) ----
        const uint4v* Xsrc = (const uint4v*)Xpk + ((size_t)t * 32 + grp) * 64 + lane;
        uint4v xft[8];
#pragma unroll
        for (int k = 0; k < 8; ++k) {
            asm volatile("global_load_dwordx4 %0, %1, off"
                         : "=v"(xft[k]) : "v"(Xsrc + k * 256));
        }
        uint4v tmp[8];
        const uint4v* Hsrc = (const uint4v*)Hbuf + (size_t)sIn * 8192 +
                             (size_t)grp * 2048;
        if (t > 0) {
#pragma unroll
            for (int i = 0; i < 8; ++i) {
                asm volatile("global_load_dwordx4 %0, %1, off sc0 sc1"
                             : "=v"(tmp[i]) : "v"(Hsrc + i * 256 + tid));
            }
            // wait xf (oldest: prev stores + xf); H stays in flight
            asm volatile("s_waitcnt vmcnt(8)" ::: "memory");
        } else {
            asm volatile("s_waitcnt vmcnt(0)" ::: "memory");
        }
        __builtin_amdgcn_sched_barrier(0);

        // ---- X-MFMAs (own tile) under the H shadow ----
        f32x4 accX = {0.f, 0.f, 0.f, 0.f};
#pragma unroll
        for (int k = 0; k < 8; ++k) {
            half8 bf = __builtin_bit_cast(half8, xft[k]);
            accX = __builtin_amdgcn_mfma_f32_16x16x32_f16(xa[k], bf, accX, 0, 0, 0);
        }

        // ---- H partials for all 4 tiles over this wave's 8 resident kc ----
        f32x4 accT[4];
#pragma unroll
        for (int jl = 0; jl < 4; ++jl) accT[jl] = (f32x4){0.f, 0.f, 0.f, 0.f};

        if (t > 0) {
            // poll: re-read ONLY still-poison vectors (good words are final)
            for (;;) {
                asm volatile("s_waitcnt vmcnt(0)" ::: "memory");
                __builtin_amdgcn_sched_barrier(0);
                int bad[8];
                int any = 0;
#pragma unroll
                for (int i = 0; i < 8; ++i) {
                    bad[i] = (tmp[i].x == 0xFFFFFFFFu) | (tmp[i].y == 0xFFFFFFFFu) |
                             (tmp[i].z == 0xFFFFFFFFu) | (tmp[i].w == 0xFFFFFFFFu);
                    any |= bad[i];
                }
                if (__all(any == 0)) break;
#pragma unroll
                for (int i = 0; i < 8; ++i) {
                    if (bad[i]) {
                        asm volatile("global_load_dwordx4 %0, %1, off sc0 sc1"
                                     : "=v"(tmp[i]) : "v"(Hsrc + i * 256 + tid));
                    }
                }
                __builtin_amdgcn_s_sleep(1);
            }

            // tmp[i] = B-frag(kc = i*4 + w); A-frags for all 4 tiles from LDS
#pragma unroll
            for (int i = 0; i < 8; ++i) {
                const int kc = i * 4 + w;
                half8 bf = __builtin_bit_cast(half8, tmp[i]);
#pragma unroll
                for (int jl = 0; jl < 4; ++jl) {
                    half8 a = Ald8[jl * 2048 + kc * 64];
                    accT[jl] = __builtin_amdgcn_mfma_f32_16x16x32_f16(a, bf, accT[jl], 0, 0, 0);
                }
            }
        }

        // ---- cross-wave K-reduction via alternating pp buffer ----
#pragma unroll
        for (int jl = 0; jl < 4; ++jl)
            pp[pb][(w * 4 + jl) * 64 + lane] = accT[jl];
        __syncthreads();   // partials ready (single barrier per step)

        f32x4 s = accX;
#pragma unroll
        for (int w2 = 0; w2 < 4; ++w2)
            s += pp[pb][(w2 * 4 + w) * 64 + lane];

        // ---- gates fully in-register ----
        float pi = s[0] + bsum[0];
        float pf = s[1] + bsum[1];
        float pg = s[2] + bsum[2];
        float po = s[3] + bsum[3];
        float ig = sigmoidf_(pi), fg = sigmoidf_(pf);
        float gg = tanhf_(pg),    og = sigmoidf_(po);
        c_reg = fg * c_reg + ig * gg;
        float h = og * tanhf_(c_reg);

        // ---- publish h(t) EVERY step (slot 63 at t=511 feeds hdec_mfma) ----
        float hp = __shfl_xor(h, 16);    // partner q^1 -> dim d^1
        if (!(q & 1)) {
            _Float16 h0 = (_Float16)h, h1 = (_Float16)hp;
            unsigned int pk = (unsigned int)__builtin_bit_cast(unsigned short, h0) |
                              ((unsigned int)__builtin_bit_cast(unsigned short, h1) << 16);
            unsigned int* po_ = (unsigned int*)(Hbuf + (size_t)sOut * 65536 + pidx);
            asm volatile("global_store_dword %0, %1, off sc0 sc1"
                         :: "v"(po_), "v"(pk) : "memory");
            unsigned int* pz = (unsigned int*)(Hbuf + (size_t)sPoi * 65536 + pidx);
            unsigned int poison = 0xFFFFFFFFu;
            asm volatile("global_store_dword %0, %1, off sc0 sc1"
                         :: "v"(pz), "v"(poison) : "memory");
        }
        // stores drained by next step's poll vmcnt; no end-of-loop barrier
    }

    // ---- final state for decoder ----
    cT[d * 64 + b] = c_reg;
    // final h is in Hbuf slot (TT_-1)&63 in B-frag layout (read by hdec_mfma)
}

// ---------------- hdec_mfma: hdecg = h_final @ dec_Whh^T + biases ----------------
__global__ __launch_bounds__(256)
void hdec_mfma(const _Float16* __restrict__ Ahhpk,
               const _Float16* __restrict__ Hfin,
               const float* __restrict__ biascd,
               float* __restrict__ hdecg)
{
    const int tid = threadIdx.x;
    const int lane = tid & 63, w = tid >> 6;
    const int jt = blockIdx.x * 4 + w;
    const int q = lane >> 4, bl = lane & 15;

    const half8* A8 = (const half8*)Ahhpk + ((size_t)jt * 32) * 64 + lane;
    const half8* H8 = (const half8*)Hfin + lane;

    f32x4 acc[4];
#pragma unroll
    for (int g = 0; g < 4; ++g) acc[g] = (f32x4){0.f, 0.f, 0.f, 0.f};
#pragma unroll 4
    for (int kc = 0; kc < 32; ++kc) {
        half8 a = A8[kc * 64];
#pragma unroll
        for (int g = 0; g < 4; ++g) {
            half8 bf = H8[g * 2048 + kc * 64];
            acc[g] = __builtin_amdgcn_mfma_f32_16x16x32_f16(a, bf, acc[g], 0, 0, 0);
        }
    }
    int d = jt * 4 + q;
#pragma unroll
    for (int g = 0; g < 4; ++g)
#pragma unroll
        for (int r = 0; r < 4; ++r)
            hdecg[((size_t)r * HH + d) * 64 + g * 16 + bl] = acc[g][r] + biascd[r * HH + d];
}

// ---------------- MFMA decoder v2: 2 t-tiles per WG (A-reads amortized) ----------------
// grid 1024 = (tp = bid>>2 in [0,256), bq4 = bid&3); t = tp*2 + {0,1}.
// Phase 1: per A-frag read -> 2 MFMAs (one per t); gates share cT/hdecg loads.
// Phase 2: FC per t sequentially (outl reused).
__global__ __launch_bounds__(256)
void dec_mfma2(const _Float16* __restrict__ Adecpk,
               const _Float16* __restrict__ fcWpk,
               const _Float16* __restrict__ Xpk,
               const float* __restrict__ hdecg,
               const float* __restrict__ cT,
               const float* __restrict__ fcb,
               float* __restrict__ out)
{
    __shared__ __align__(16) _Float16 Hn[2][32 * 64 * 8];   // 64 KB
    __shared__ __align__(16) float outl[16][260];           // ~16.6 KB
    const int tid = threadIdx.x;
    const int lane = tid & 63, w = tid >> 6;
    const int tp = blockIdx.x >> 2, bq4 = blockIdx.x & 3;
    const int t0 = tp * 2;
    const int q = lane >> 4, bl = lane & 15;
    const int bg = bq4 * 16 + bl;

    const half8* X0 = (const half8*)Xpk + ((size_t)t0 * 32 + bq4) * 64 + lane;
    const half8* X1 = (const half8*)Xpk + ((size_t)(t0 + 1) * 32 + bq4) * 64 + lane;
    half8 xf0[8], xf1[8];
#pragma unroll
    for (int k = 0; k < 8; ++k) { xf0[k] = X0[k * 256]; xf1[k] = X1[k * 256]; }

    const half8* AD = (const half8*)Adecpk + lane;
    for (int dqi = 0; dqi < 32; ++dqi) {
        int dq = w * 32 + dqi;
#pragma unroll
        for (int t2 = 0; t2 < 2; ++t2) {
            f32x4 acc0 = {0.f, 0.f, 0.f, 0.f};
            f32x4 acc1 = {0.f, 0.f, 0.f, 0.f};
#pragma unroll
            for (int kc2 = 0; kc2 < 8; ++kc2) {
                half8 a = AD[((size_t)(dq * 2 + t2) * 8 + kc2) * 64];
                acc0 = __builtin_amdgcn_mfma_f32_16x16x32_f16(a, xf0[kc2], acc0, 0, 0, 0);
                acc1 = __builtin_amdgcn_mfma_f32_16x16x32_f16(a, xf1[kc2], acc1, 0, 0, 0);
            }
            int d = dq * 8 + t2 * 4 + q;
            float cv = cT[d * 64 + bg];
            float hbi = hdecg[(size_t)(0 * HH + d) * 64 + bg];
            float hbf = hdecg[(size_t)(1 * HH + d) * 64 + bg];
            float hbg = hdecg[(size_t)(2 * HH + d) * 64 + bg];
            float hbo = hdecg[(size_t)(3 * HH + d) * 64 + bg];
            unsigned int hidx = (((unsigned)d >> 5) * 64 +
                                 (((unsigned)d >> 3) & 3) * 16 + bl) * 8 + (d & 7);
            {
                float ig = sigmoidf_(acc0[0] + hbi), fg = sigmoidf_(acc0[1] + hbf);
                float gg = tanhf_(acc0[2] + hbg),    og = sigmoidf_(acc0[3] + hbo);
                float cn = fg * cv + ig * gg;
                Hn[0][hidx] = (_Float16)(og * tanhf_(cn));
            }
            {
                float ig = sigmoidf_(acc1[0] + hbi), fg = sigmoidf_(acc1[1] + hbf);
                float gg = tanhf_(acc1[2] + hbg),    og = sigmoidf_(acc1[3] + hbo);
                float cn = fg * cv + ig * gg;
                Hn[1][hidx] = (_Float16)(og * tanhf_(cn));
            }
        }
    }
    __syncthreads();

    const half8* FW = (const half8*)fcWpk + lane;
#pragma unroll
    for (int tt = 0; tt < 2; ++tt) {
        const half8* Hn8 = (const half8*)&Hn[tt][0] + lane;
#pragma unroll
        for (int oti = 0; oti < 4; ++oti) {
            int ot = w * 4 + oti;
            f32x4 acc = {0.f, 0.f, 0.f, 0.f};
            for (int kc = 0; kc < 32; ++kc) {
                half8 a  = FW[((size_t)ot * 32 + kc) * 64];
                half8 bf = Hn8[kc * 64];
                acc = __builtin_amdgcn_mfma_f32_16x16x32_f16(a, bf, acc, 0, 0, 0);
            }
#pragma unroll
            for (int r = 0; r < 4; ++r) {
                int o = ot * 16 + q * 4 + r;
                outl[bl][o] = acc[r] + fcb[o];
            }
        }
        __syncthreads();   // outl ready
#pragma unroll
        for (int i = 0; i < 16; ++i) {
            int b = bq4 * 16 + i;
            out[((size_t)b * TT_ + t0 + tt) * OO + tid] = outl[i][tid];
        }
        __syncthreads();   // protect outl before next tt overwrites
    }
}

extern "C" void kernel_launch(void* const* d_in, const int* in_sizes, int n_in,
                              void* d_out, int out_size, void* d_ws, size_t ws_size,
                              hipStream_t stream) {
    const float* x    = (const float*)d_in[0];
    const float* eWih = (const float*)d_in[1];
    const float* eWhh = (const float*)d_in[2];
    const float* ebih = (const float*)d_in[3];
    const float* ebhh = (const float*)d_in[4];
    const float* dWih = (const float*)d_in[5];
    const float* dWhh = (const float*)d_in[6];
    const float* dbih = (const float*)d_in[7];
    const float* dbhh = (const float*)d_in[8];
    const float* fcW  = (const float*)d_in[9];
    const float* fcb  = (const float*)d_in[10];

    // ws layout (f32 words): cT 65536 | hdecg 262144 | biasc 4096 | biascd 4096 |
    // then fp16: Hbuf 64x65536 = 4194304 | Apk 5242880 | Xpk 8388608 |
    // Adecpk 1048576 | fcWpk 262144 | Ahhpk 4194304  (~48 MB total)
    float* ws     = (float*)d_ws;
    float* cT     = ws;
    float* hdecg  = ws + 65536;
    float* biasc  = ws + 327680;
    float* biascd = ws + 331776;
    _Float16* fp  = (_Float16*)(ws + 335872);
    _Float16* Hbuf = fp;
    _Float16* Apk  = fp + 4194304;
    _Float16* Xpk  = Apk + 5242880;
    _Float16* Adecpk = Xpk + 8388608;
    _Float16* fcWpk  = Adecpk + 1048576;
    _Float16* Ahhpk  = fcWpk + 262144;

    pack_all<<<dim3(9888), dim3(256), 0, stream>>>(
        eWhh, eWih, x, ebih, ebhh, dbih, dbhh, dWih, fcW, dWhh,
        Apk, Xpk, biasc, biascd, Adecpk, fcWpk, Ahhpk, Hbuf);

    enc_persist<<<dim3(256), dim3(256), 0, stream>>>(
        Apk, Xpk, Hbuf, biasc, cT);

    const _Float16* Hfin = Hbuf + (size_t)((TT_ - 1) & 63) * 65536;
    hdec_mfma<<<dim3(64), dim3(256), 0, stream>>>(Ahhpk, Hfin, biascd, hdecg);
    dec_mfma2<<<dim3(1024), dim3(256), 0, stream>>>(Adecpk, fcWpk, Xpk, hdecg, cT,
                                                    fcb, (float*)d_out);
}

// Round 19
// 1488.711 us; speedup vs baseline: 1.1792x; 1.1792x over previous
//
#include <hip/hip_runtime.h>
#include <hip/hip_bf16.h>

#define BB 64
#define TT_ 512
#define IN_ 256
#define HH 1024
#define G4 4096
#define OO 256

typedef _Float16 half8 __attribute__((ext_vector_type(8)));
typedef float f32x4 __attribute__((ext_vector_type(4)));
typedef unsigned int uint4v __attribute__((ext_vector_type(4)));

__device__ __forceinline__ float sigmoidf_(float v) {
    return 1.f / (1.f + __expf(-v));
}
__device__ __forceinline__ float tanhf_(float v) {
    float vc = fminf(fmaxf(v, -15.f), 15.f);
    float e = __expf(2.f * vc);
    return (e - 1.f) / (e + 1.f);
}

// ---------------- fused pack kernel ----------------
// One launch does all weight/x packs + Hbuf poison (disjoint outputs).
__global__ __launch_bounds__(256)
void pack_all(const float* __restrict__ eWhh, const float* __restrict__ eWih,
              const float* __restrict__ x,
              const float* __restrict__ ebih, const float* __restrict__ ebhh,
              const float* __restrict__ dbih, const float* __restrict__ dbhh,
              const float* __restrict__ dWih, const float* __restrict__ fcW,
              const float* __restrict__ dWhh,
              _Float16* __restrict__ Apk, _Float16* __restrict__ Xpk,
              float* __restrict__ biasc, float* __restrict__ biascd,
              _Float16* __restrict__ Adecpk, _Float16* __restrict__ fcWpk,
              _Float16* __restrict__ Ahhpk, _Float16* __restrict__ Hbuf)
{
    const int blk = blockIdx.x;
    if (blk < 2560) {
        int id = blk * 256 + threadIdx.x;             // < 655360
        int dq  = id / 5120;
        int r1  = id - dq * 5120;
        int t2  = r1 / 2560;
        int r2  = r1 - t2 * 2560;
        int kc  = r2 >> 6, l = r2 & 63;
        int rD  = l & 15;
        int g   = rD & 3, ddl = rD >> 2;
        int d   = dq * 8 + t2 * 4 + ddl;
        int j   = g * HH + d;
        int k0  = kc * 32 + ((l >> 4) << 3);
        half8 v;
        if (kc < 32) {
            const float* s = eWhh + (size_t)j * HH + k0;
#pragma unroll
            for (int e = 0; e < 8; ++e) v[e] = (_Float16)s[e];
        } else {
            const float* s = eWih + (size_t)j * IN_ + (k0 - 1024);
#pragma unroll
            for (int e = 0; e < 8; ++e) v[e] = (_Float16)s[e];
        }
        ((half8*)Apk)[id] = v;
    } else if (blk < 6656) {
        int id = (blk - 2560) * 256 + threadIdx.x;    // < 1048576
        int l = id & 63, bt = (id >> 6) & 3, kc2 = (id >> 8) & 7, t = id >> 11;
        int b  = bt * 16 + (l & 15);
        int i0 = kc2 * 32 + ((l >> 4) << 3);
        const float* s = x + ((size_t)b * TT_ + t) * IN_ + i0;
        half8 v;
#pragma unroll
        for (int e = 0; e < 8; ++e) v[e] = (_Float16)s[e];
        ((half8*)Xpk)[id] = v;
    } else if (blk < 6672) {
        int j = (blk - 6656) * 256 + threadIdx.x;
        if (j < G4) biasc[j] = ebih[j] + ebhh[j];
    } else if (blk < 6688) {
        int j = (blk - 6672) * 256 + threadIdx.x;
        if (j < G4) biascd[j] = dbih[j] + dbhh[j];
    } else if (blk < 7200) {
        int id = (blk - 6688) * 256 + threadIdx.x;    // < 131072
        int dq = id >> 10;
        int r1 = id & 1023;
        int t2 = r1 >> 9;
        int r2 = r1 & 511;
        int kc2 = r2 >> 6, l = r2 & 63;
        int rD = l & 15, g = rD & 3, ddl = rD >> 2;
        int d  = dq * 8 + t2 * 4 + ddl;
        int j  = g * HH + d;
        int k0 = kc2 * 32 + ((l >> 4) << 3);
        const float* s = dWih + (size_t)j * IN_ + k0;
        half8 v;
#pragma unroll
        for (int e = 0; e < 8; ++e) v[e] = (_Float16)s[e];
        ((half8*)Adecpk)[id] = v;
    } else if (blk < 7328) {
        int id = (blk - 7200) * 256 + threadIdx.x;    // < 32768
        int ot = id >> 11;
        int r  = id & 2047;
        int kc = r >> 6, l = r & 63;
        int o  = ot * 16 + (l & 15);
        int k0 = kc * 32 + ((l >> 4) << 3);
        const float* s = fcW + (size_t)o * HH + k0;
        half8 v;
#pragma unroll
        for (int e = 0; e < 8; ++e) v[e] = (_Float16)s[e];
        ((half8*)fcWpk)[id] = v;
    } else if (blk < 9376) {
        int id = (blk - 7328) * 256 + threadIdx.x;    // < 524288
        int jt = id >> 11;
        int r  = id & 2047;
        int kc = r >> 6, l = r & 63;
        int rD = l & 15, g = rD & 3, ddl = rD >> 2;
        int d  = jt * 4 + ddl;
        int j  = g * HH + d;
        int k0 = kc * 32 + ((l >> 4) << 3);
        const float* s = dWhh + (size_t)j * HH + k0;
        half8 v;
#pragma unroll
        for (int e = 0; e < 8; ++e) v[e] = (_Float16)s[e];
        ((half8*)Ahhpk)[id] = v;
    } else {
        // poison Hbuf: 512 blocks x 256 thr x 4 uint4v = 8 MB of 0xFF
        uint4v* H4 = (uint4v*)Hbuf;
        int base = (blk - 9376) * 1024 + threadIdx.x;
        uint4v p = {0xFFFFFFFFu, 0xFFFFFFFFu, 0xFFFFFFFFu, 0xFFFFFFFFu};
#pragma unroll
        for (int i = 0; i < 4; ++i) H4[base + i * 256] = p;
    }
}

// ---------------- persistent encoder (R17 verbatim): dataflow, 2 barriers/step ----------------
// grid 256 = (dq16 = bid>>2, grp = bid&3), block 256 (4 waves, 1 WG/CU).
// Register-resident H (tmp[i] IS B-frag kc=i*4+w); wave w computes partials
// for all 4 tiles over its 8 resident kc; 16KB LDS exchange with TWO barriers
// per step (the second keeps waves phase-locked -> publish window tight ->
// poll converges in ~1 round; R18's single-barrier variant regressed).
// Publish EVERY step: slot (TT_-1)&63 holds final h (B-frag) for hdec_mfma.
__global__ __launch_bounds__(256, 1)
void enc_persist(const _Float16* __restrict__ Apk,
                 const _Float16* __restrict__ Xpk,
                 _Float16* __restrict__ Hbuf,
                 const float* __restrict__ biasc,
                 float* __restrict__ cT)
{
    __shared__ __align__(16) _Float16 Ald[4 * 32 * 64 * 8];   // 128 KB
    __shared__ __align__(16) f32x4 pp[16 * 64];               // 16 KB
    const int tid  = threadIdx.x;
    const int lane = tid & 63, w = tid >> 6;
    const int dq16 = blockIdx.x >> 2, grp = blockIdx.x & 3;
    const int q = lane >> 4, bl = lane & 15;
    const int d = dq16 * 16 + w * 4 + q;         // this thread's dim (own tile)
    const int b = grp * 16 + bl;                 // this thread's batch

    // ---- one-time: each wave loads its tile's 32 Whh A-frags -> LDS ----
    {
        const half8* src = (const half8*)Apk + ((size_t)(dq16 * 4 + w) * 40) * 64 + lane;
        half8* dst = (half8*)Ald + (size_t)w * 2048 + lane;
#pragma unroll
        for (int kc = 0; kc < 32; ++kc) dst[kc * 64] = src[kc * 64];
    }
    // ---- one-time: own tile's Wih A-frags -> registers (8 frags) ----
    half8 xa[8];
    {
        const half8* src = (const half8*)Apk + ((size_t)(dq16 * 4 + w) * 40 + 32) * 64 + lane;
#pragma unroll
        for (int k = 0; k < 8; ++k) xa[k] = src[k * 64];
    }

    float bsum[4];
#pragma unroll
    for (int g = 0; g < 4; ++g) bsum[g] = biasc[g * HH + d];

    const half8* Ald8 = (const half8*)Ald + lane;   // + jl*2048 + kc*64

    // publish half-index within a slot (pair of dims d, d^1 packed as u32),
    // in fp16 units; slot stride = 65536 fp16
    const unsigned int pidx = ((unsigned)grp * 2048 + ((unsigned)d >> 5) * 64 +
                               (((unsigned)d >> 3) & 3) * 16 + bl) * 8 + (d & 7);

    float c_reg = 0.f;
    __syncthreads();   // A-LDS ready

    for (int t = 0; t < TT_; ++t) {
        const int sIn  = (t - 1) & 63;
        const int sOut = t & 63;
        const int sPoi = (t + 8) & 63;

        // ---- issue xf loads FIRST (plain), then H (sc0sc1) ----
        const uint4v* Xsrc = (const uint4v*)Xpk + ((size_t)t * 32 + grp) * 64 + lane;
        uint4v xft[8];
#pragma unroll
        for (int k = 0; k < 8; ++k) {
            asm volatile("global_load_dwordx4 %0, %1, off"
                         : "=v"(xft[k]) : "v"(Xsrc + k * 256));
        }
        uint4v tmp[8];
        const uint4v* Hsrc = (const uint4v*)Hbuf + (size_t)sIn * 8192 +
                             (size_t)grp * 2048;
        if (t > 0) {
#pragma unroll
            for (int i = 0; i < 8; ++i) {
                asm volatile("global_load_dwordx4 %0, %1, off sc0 sc1"
                             : "=v"(tmp[i]) : "v"(Hsrc + i * 256 + tid));
            }
            // wait xf (oldest 8 + prev-iter stores); H stays in flight
            asm volatile("s_waitcnt vmcnt(8)" ::: "memory");
        } else {
            asm volatile("s_waitcnt vmcnt(0)" ::: "memory");
        }
        __builtin_amdgcn_sched_barrier(0);

        // ---- X-MFMAs (own tile) under the H shadow ----
        f32x4 accX = {0.f, 0.f, 0.f, 0.f};
#pragma unroll
        for (int k = 0; k < 8; ++k) {
            half8 bf = __builtin_bit_cast(half8, xft[k]);
            accX = __builtin_amdgcn_mfma_f32_16x16x32_f16(xa[k], bf, accX, 0, 0, 0);
        }

        // ---- H partials for all 4 tiles over this wave's 8 resident kc ----
        f32x4 accT[4];
#pragma unroll
        for (int jl = 0; jl < 4; ++jl) accT[jl] = (f32x4){0.f, 0.f, 0.f, 0.f};

        if (t > 0) {
            // poll: re-read ONLY still-poison vectors (good words are final)
            for (;;) {
                asm volatile("s_waitcnt vmcnt(0)" ::: "memory");
                __builtin_amdgcn_sched_barrier(0);
                int bad[8];
                int any = 0;
#pragma unroll
                for (int i = 0; i < 8; ++i) {
                    bad[i] = (tmp[i].x == 0xFFFFFFFFu) | (tmp[i].y == 0xFFFFFFFFu) |
                             (tmp[i].z == 0xFFFFFFFFu) | (tmp[i].w == 0xFFFFFFFFu);
                    any |= bad[i];
                }
                if (__all(any == 0)) break;
#pragma unroll
                for (int i = 0; i < 8; ++i) {
                    if (bad[i]) {
                        asm volatile("global_load_dwordx4 %0, %1, off sc0 sc1"
                                     : "=v"(tmp[i]) : "v"(Hsrc + i * 256 + tid));
                    }
                }
                __builtin_amdgcn_s_sleep(1);
            }

            // tmp[i] = B-frag(kc = i*4 + w); A-frags for all 4 tiles from LDS
#pragma unroll
            for (int i = 0; i < 8; ++i) {
                const int kc = i * 4 + w;
                half8 bf = __builtin_bit_cast(half8, tmp[i]);
#pragma unroll
                for (int jl = 0; jl < 4; ++jl) {
                    half8 a = Ald8[jl * 2048 + kc * 64];
                    accT[jl] = __builtin_amdgcn_mfma_f32_16x16x32_f16(a, bf, accT[jl], 0, 0, 0);
                }
            }
        }

        // ---- cross-wave K-reduction: pp[w][jl] = accT[jl]; owner jl sums ----
#pragma unroll
        for (int jl = 0; jl < 4; ++jl)
            pp[(w * 4 + jl) * 64 + lane] = accT[jl];
        __syncthreads();   // partials ready

        f32x4 s = accX;
#pragma unroll
        for (int w2 = 0; w2 < 4; ++w2)
            s += pp[(w2 * 4 + w) * 64 + lane];

        // ---- gates fully in-register ----
        float pi = s[0] + bsum[0];
        float pf = s[1] + bsum[1];
        float pg = s[2] + bsum[2];
        float po = s[3] + bsum[3];
        float ig = sigmoidf_(pi), fg = sigmoidf_(pf);
        float gg = tanhf_(pg),    og = sigmoidf_(po);
        c_reg = fg * c_reg + ig * gg;
        float h = og * tanhf_(c_reg);

        // ---- publish h(t) EVERY step (slot 63 at t=511 feeds hdec_mfma) ----
        float hp = __shfl_xor(h, 16);    // partner q^1 -> dim d^1
        if (!(q & 1)) {
            _Float16 h0 = (_Float16)h, h1 = (_Float16)hp;
            unsigned int pk = (unsigned int)__builtin_bit_cast(unsigned short, h0) |
                              ((unsigned int)__builtin_bit_cast(unsigned short, h1) << 16);
            unsigned int* po_ = (unsigned int*)(Hbuf + (size_t)sOut * 65536 + pidx);
            asm volatile("global_store_dword %0, %1, off sc0 sc1"
                         :: "v"(po_), "v"(pk) : "memory");
            unsigned int* pz = (unsigned int*)(Hbuf + (size_t)sPoi * 65536 + pidx);
            unsigned int poison = 0xFFFFFFFFu;
            asm volatile("global_store_dword %0, %1, off sc0 sc1"
                         :: "v"(pz), "v"(poison) : "memory");
        }
        // stores drained by next step's poll vmcnt; no flags, no drains here

        if (t < TT_ - 1) __syncthreads();   // phase-lock waves (R18: removing this hurt)
    }

    // ---- final state for decoder ----
    cT[d * 64 + b] = c_reg;
    // final h is in Hbuf slot (TT_-1)&63 in B-frag layout (read by hdec_mfma)
}

// ---------------- hdec_mfma: hdecg = h_final @ dec_Whh^T + biases ----------------
__global__ __launch_bounds__(256)
void hdec_mfma(const _Float16* __restrict__ Ahhpk,
               const _Float16* __restrict__ Hfin,
               const float* __restrict__ biascd,
               float* __restrict__ hdecg)
{
    const int tid = threadIdx.x;
    const int lane = tid & 63, w = tid >> 6;
    const int jt = blockIdx.x * 4 + w;
    const int q = lane >> 4, bl = lane & 15;

    const half8* A8 = (const half8*)Ahhpk + ((size_t)jt * 32) * 64 + lane;
    const half8* H8 = (const half8*)Hfin + lane;

    f32x4 acc[4];
#pragma unroll
    for (int g = 0; g < 4; ++g) acc[g] = (f32x4){0.f, 0.f, 0.f, 0.f};
#pragma unroll 4
    for (int kc = 0; kc < 32; ++kc) {
        half8 a = A8[kc * 64];
#pragma unroll
        for (int g = 0; g < 4; ++g) {
            half8 bf = H8[g * 2048 + kc * 64];
            acc[g] = __builtin_amdgcn_mfma_f32_16x16x32_f16(a, bf, acc[g], 0, 0, 0);
        }
    }
    int d = jt * 4 + q;
#pragma unroll
    for (int g = 0; g < 4; ++g)
#pragma unroll
        for (int r = 0; r < 4; ++r)
            hdecg[((size_t)r * HH + d) * 64 + g * 16 + bl] = acc[g][r] + biascd[r * HH + d];
}

// ---------------- MFMA decoder (R17 verbatim) ----------------
__global__ __launch_bounds__(256)
void dec_mfma(const _Float16* __restrict__ Adecpk,
              const _Float16* __restrict__ fcWpk,
              const _Float16* __restrict__ Xpk,
              const float* __restrict__ hdecg,
              const float* __restrict__ cT,
              const float* __restrict__ fcb,
              float* __restrict__ out)
{
    __shared__ __align__(16) _Float16 Hn[32 * 64 * 8];   // 32 KB
    __shared__ __align__(16) float outl[16][260];
    const int tid = threadIdx.x;
    const int lane = tid & 63, w = tid >> 6;
    const int t = blockIdx.x >> 2, bq4 = blockIdx.x & 3;
    const int q = lane >> 4, bl = lane & 15;
    const int bg = bq4 * 16 + bl;

    const half8* X8 = (const half8*)Xpk + ((size_t)t * 32 + bq4) * 64 + lane;
    half8 xf[8];
#pragma unroll
    for (int kc2 = 0; kc2 < 8; ++kc2) xf[kc2] = X8[kc2 * 256];

    const half8* AD = (const half8*)Adecpk + lane;
    for (int dqi = 0; dqi < 32; ++dqi) {
        int dq = w * 32 + dqi;
#pragma unroll
        for (int t2 = 0; t2 < 2; ++t2) {
            f32x4 acc = {0.f, 0.f, 0.f, 0.f};
#pragma unroll
            for (int kc2 = 0; kc2 < 8; ++kc2) {
                half8 a = AD[((size_t)(dq * 2 + t2) * 8 + kc2) * 64];
                acc = __builtin_amdgcn_mfma_f32_16x16x32_f16(a, xf[kc2], acc, 0, 0, 0);
            }
            int d = dq * 8 + t2 * 4 + q;
            float cv = cT[d * 64 + bg];
            float pi = acc[0] + hdecg[(size_t)(0 * HH + d) * 64 + bg];
            float pf = acc[1] + hdecg[(size_t)(1 * HH + d) * 64 + bg];
            float pg = acc[2] + hdecg[(size_t)(2 * HH + d) * 64 + bg];
            float po = acc[3] + hdecg[(size_t)(3 * HH + d) * 64 + bg];
            float ig = sigmoidf_(pi), fg = sigmoidf_(pf);
            float gg = tanhf_(pg),    og = sigmoidf_(po);
            float cn = fg * cv + ig * gg;
            float h = og * tanhf_(cn);
            Hn[((d >> 5) * 64 + ((d >> 3) & 3) * 16 + bl) * 8 + (d & 7)] = (_Float16)h;
        }
    }
    __syncthreads();

    const half8* Hn8 = (const half8*)Hn + lane;
    const half8* FW = (const half8*)fcWpk + lane;
#pragma unroll
    for (int oti = 0; oti < 4; ++oti) {
        int ot = w * 4 + oti;
        f32x4 acc = {0.f, 0.f, 0.f, 0.f};
        for (int kc = 0; kc < 32; ++kc) {
            half8 a  = FW[((size_t)ot * 32 + kc) * 64];
            half8 bf = Hn8[kc * 64];
            acc = __builtin_amdgcn_mfma_f32_16x16x32_f16(a, bf, acc, 0, 0, 0);
        }
#pragma unroll
        for (int r = 0; r < 4; ++r) {
            int o = ot * 16 + q * 4 + r;
            outl[bl][o] = acc[r] + fcb[o];
        }
    }
    __syncthreads();

#pragma unroll
    for (int i = 0; i < 16; ++i) {
        int b = bq4 * 16 + i;
        out[((size_t)b * TT_ + t) * OO + tid] = outl[i][tid];
    }
}

extern "C" void kernel_launch(void* const* d_in, const int* in_sizes, int n_in,
                              void* d_out, int out_size, void* d_ws, size_t ws_size,
                              hipStream_t stream) {
    const float* x    = (const float*)d_in[0];
    const float* eWih = (const float*)d_in[1];
    const float* eWhh = (const float*)d_in[2];
    const float* ebih = (const float*)d_in[3];
    const float* ebhh = (const float*)d_in[4];
    const float* dWih = (const float*)d_in[5];
    const float* dWhh = (const float*)d_in[6];
    const float* dbih = (const float*)d_in[7];
    const float* dbhh = (const float*)d_in[8];
    const float* fcW  = (const float*)d_in[9];
    const float* fcb  = (const float*)d_in[10];

    // ws layout (f32 words): cT 65536 | hdecg 262144 | biasc 4096 | biascd 4096 |
    // then fp16: Hbuf 64x65536 = 4194304 | Apk 5242880 | Xpk 8388608 |
    // Adecpk 1048576 | fcWpk 262144 | Ahhpk 4194304  (~48 MB total)
    float* ws     = (float*)d_ws;
    float* cT     = ws;
    float* hdecg  = ws + 65536;
    float* biasc  = ws + 327680;
    float* biascd = ws + 331776;
    _Float16* fp  = (_Float16*)(ws + 335872);
    _Float16* Hbuf = fp;
    _Float16* Apk  = fp + 4194304;
    _Float16* Xpk  = Apk + 5242880;
    _Float16* Adecpk = Xpk + 8388608;
    _Float16* fcWpk  = Adecpk + 1048576;
    _Float16* Ahhpk  = fcWpk + 262144;

    pack_all<<<dim3(9888), dim3(256), 0, stream>>>(
        eWhh, eWih, x, ebih, ebhh, dbih, dbhh, dWih, fcW, dWhh,
        Apk, Xpk, biasc, biascd, Adecpk, fcWpk, Ahhpk, Hbuf);

    enc_persist<<<dim3(256), dim3(256), 0, stream>>>(
        Apk, Xpk, Hbuf, biasc, cT);

    const _Float16* Hfin = Hbuf + (size_t)((TT_ - 1) & 63) * 65536;
    hdec_mfma<<<dim3(64), dim3(256), 0, stream>>>(Ahhpk, Hfin, biascd, hdecg);
    dec_mfma<<<dim3(2048), dim3(256), 0, stream>>>(Adecpk, fcWpk, Xpk, hdecg, cT,
                                                   fcb, (float*)d_out);
}